// Round 4
// baseline (196.072 us; speedup 1.0000x reference)
//
#include <hip/hip_runtime.h>
#include <cstdint>

// Linear-chain CRF log-partition, B=64, T=4096, S=64.
// R4: chunked scan NC=819 x L=5 (819*5=4095), fwd/bwd chunk maps via
// mfma_f32_16x16x32_bf16 (16 chains/wave), rank-1 recombination.
// 6656 one-wave workgroups (6.5 waves/SIMD) to hide the per-step serial
// latency (R3 was 2.25/SIMD, 66% idle). No renorm (fp32 range suffices for
// 5 steps; fwd scale cancels, bwd scale absorbed by log2f). Native __bf16
// packing (v_cvt_pk_bf16_f32). Single LDS transpose buffer (DS in-order).

#define B_    64
#define T_    4096
#define S_    64
#define L_    5
#define NC_   819                 // 819*5 = 4095 = T_-1
#define WPB_  52                  // ceil(819/16) waves per batch per direction
#define CPB_  832                 // padded chains per batch (52*16)
#define LOG2E 1.44269504088896340736f

typedef float  f32x4  __attribute__((ext_vector_type(4)));
typedef __bf16 bf16x8 __attribute__((ext_vector_type(8)));
union U4B { uint4 u; bf16x8 b; };

__global__ __launch_bounds__(64, 6) void crf_phase1(
    const float* __restrict__ scores,      // (B,T,S)
    const float* __restrict__ transition,  // (S,S) [from,to]
    float* __restrict__ Ybuf, float* __restrict__ Zbuf)
{
    __shared__ float tb[16][68];
    const int wid  = blockIdx.x;
    const bool bwd = wid >= (B_ * WPB_);
    const int wl   = bwd ? wid - B_ * WPB_ : wid;
    const int b    = wl / WPB_, wg = wl % WPB_;
    const int lane = threadIdx.x, g = lane >> 4, l = lane & 15;

    // ---- E fragments in registers: fwd B[k][n]=exp(T[k][n]); bwd =exp(T[n][k])
    bf16x8 BE[2][4];
    #pragma unroll
    for (int kb = 0; kb < 2; ++kb)
    #pragma unroll
    for (int nt = 0; nt < 4; ++nt) {
        bf16x8 t;
        #pragma unroll
        for (int dd = 0; dd < 4; ++dd) {
            int k0 = 32 * kb + 8 * g + 2 * dd, n = 16 * nt + l;
            float e0, e1;
            if (!bwd) { e0 = transition[k0 * 64 + n]; e1 = transition[(k0 + 1) * 64 + n]; }
            else      { e0 = transition[n * 64 + k0]; e1 = transition[n * 64 + k0 + 1]; }
            t[2 * dd]     = (__bf16)exp2f(e0 * LOG2E);
            t[2 * dd + 1] = (__bf16)exp2f(e1 * LOG2E);
        }
        BE[kb][nt] = t;
    }

    // A-side emission pointer: chain = local row l, states 8g.. contiguous
    int cl = 16 * wg + l; if (cl > NC_ - 1) cl = NC_ - 1;
    const float* ap = scores + ((size_t)b * T_ + L_ * cl + (bwd ? L_ : 0)) * S_ + 8 * g;

    f32x4 acc[4];

    auto mfma8 = [&](bf16x8 A0, bf16x8 A1) {
        #pragma unroll
        for (int nt = 0; nt < 4; ++nt) {
            f32x4 z4 = {0.f, 0.f, 0.f, 0.f};
            z4      = __builtin_amdgcn_mfma_f32_16x16x32_bf16(A0, BE[0][nt], z4, 0, 0, 0);
            acc[nt] = __builtin_amdgcn_mfma_f32_16x16x32_bf16(A1, BE[1][nt], z4, 0, 0, 0);
        }
    };
    // transpose acc (C: chain 4g+r, state 16nt+l) -> per-lane A rows, * em, pack
    auto xposeA = [&](const f32x4& c0, const f32x4& c1,
                      const f32x4& c2, const f32x4& c3, bf16x8& A0, bf16x8& A1) {
        #pragma unroll
        for (int nt = 0; nt < 4; ++nt)
            #pragma unroll
            for (int r = 0; r < 4; ++r)
                tb[4 * g + r][16 * nt + l] = acc[nt][r];
        __builtin_amdgcn_s_waitcnt(0xC07F);        // lgkmcnt(0) only
        __builtin_amdgcn_wave_barrier();
        const float* rowp = &tb[l][8 * g];
        f32x4 x0 = *(const f32x4*)rowp;
        f32x4 x1 = *(const f32x4*)(rowp + 4);
        f32x4 x2 = *(const f32x4*)(rowp + 32);
        f32x4 x3 = *(const f32x4*)(rowp + 36);
        #pragma unroll
        for (int d = 0; d < 4; ++d) {
            A0[d]     = (__bf16)(x0[d] * exp2f(c0[d] * LOG2E));
            A0[d + 4] = (__bf16)(x1[d] * exp2f(c1[d] * LOG2E));
            A1[d]     = (__bf16)(x2[d] * exp2f(c2[d] * LOG2E));
            A1[d + 4] = (__bf16)(x3[d] * exp2f(c3[d] * LOG2E));
        }
    };
    auto ldq = [&](int idx, f32x4& q0, f32x4& q1, f32x4& q2, f32x4& q3) {
        const float* p = ap + (ptrdiff_t)idx * S_;
        q0 = *(const f32x4*)p;        q1 = *(const f32x4*)(p + 4);
        q2 = *(const f32x4*)(p + 32); q3 = *(const f32x4*)(p + 36);
    };

    if (!bwd) {
        // y_c^T = 1^T * Prod_{k=0..4} E diag(em_{t0+k}); em folded into next A.
        f32x4 q0, q1, q2, q3;
        ldq(1, q0, q1, q2, q3);                    // em for A-step tt=1
        { U4B t; t.u = make_uint4(0x3F803F80u, 0x3F803F80u, 0x3F803F80u, 0x3F803F80u);
          mfma8(t.b, t.b); }                       // tt=0: A = ones
        #pragma unroll
        for (int tt = 1; tt < L_; ++tt) {
            f32x4 c0 = q0, c1 = q1, c2 = q2, c3 = q3;
            if (tt + 1 < L_) ldq(tt + 1, q0, q1, q2, q3);
            bf16x8 A0, A1;
            xposeA(c0, c1, c2, c3, A0, A1);
            mfma8(A0, A1);
        }
        // trailing emission (t = 5c+5) applied in C layout, then store y
        #pragma unroll
        for (int r = 0; r < 4; ++r) {
            int c = 16 * wg + 4 * g + r; int cc = c > NC_ - 1 ? NC_ - 1 : c;
            const float* bp = scores + ((size_t)b * T_ + L_ * cc + L_) * S_ + l;
            float* yb = Ybuf + ((size_t)b * CPB_ + c) * S_ + l;
            #pragma unroll
            for (int nt = 0; nt < 4; ++nt)
                yb[16 * nt] = acc[nt][r] * exp2f(bp[16 * nt] * LOG2E);
        }
    } else {
        // z_c = Prod E diag(em) * 1, descending t; em applied on A side.
        f32x4 q0, q1, q2, q3, n0, n1, n2, n3;
        ldq(0, q0, q1, q2, q3);                    // em at t1 = 5c+5
        ldq(-1, n0, n1, n2, n3);
        {   // i=0: A = em (z = ones)
            bf16x8 A0, A1;
            #pragma unroll
            for (int d = 0; d < 4; ++d) {
                A0[d]     = (__bf16)exp2f(q0[d] * LOG2E);
                A0[d + 4] = (__bf16)exp2f(q1[d] * LOG2E);
                A1[d]     = (__bf16)exp2f(q2[d] * LOG2E);
                A1[d + 4] = (__bf16)exp2f(q3[d] * LOG2E);
            }
            mfma8(A0, A1);
        }
        #pragma unroll
        for (int i = 1; i < L_; ++i) {
            f32x4 c0 = n0, c1 = n1, c2 = n2, c3 = n3;
            if (i + 1 < L_) ldq(-(i + 1), n0, n1, n2, n3);
            bf16x8 A0, A1;
            xposeA(c0, c1, c2, c3, A0, A1);
            mfma8(A0, A1);
        }
        #pragma unroll
        for (int r = 0; r < 4; ++r) {
            int c = 16 * wg + 4 * g + r;
            float* zb = Zbuf + ((size_t)b * CPB_ + c) * S_ + l;
            #pragma unroll
            for (int nt = 0; nt < 4; ++nt) zb[16 * nt] = acc[nt][r];
        }
    }
}

// ---------------------------------------------------------------------------
// phase2: rank-1 recombination, chunk-parallel (16 waves / batch).
// log2 Z = log2(a0.z_0) + sum_c [log2(y_c.nx_c) - log2(y_c.1)]
// (no renorm scales: fwd scale cancels in p/q; bwd scale absorbed by log2f)
// ---------------------------------------------------------------------------
__global__ __launch_bounds__(1024) void crf_phase2(
    const float* __restrict__ scores, const float* __restrict__ source,
    const float* __restrict__ sink,
    const float* __restrict__ Ybuf, const float* __restrict__ Zbuf,
    float* __restrict__ out)
{
    __shared__ float part[16];
    const int b = blockIdx.x;
    const int wv = threadIdx.x >> 6, lane = threadIdx.x & 63;
    const float esink = exp2f(sink[lane] * LOG2E);

    float acc = 0.f;
    for (int c = wv; c < NC_; c += 16) {
        float yh = Ybuf[((size_t)b * CPB_ + c) * 64 + lane];
        float nx = (c < NC_ - 1) ? Zbuf[((size_t)b * CPB_ + c + 1) * 64 + lane] : esink;
        float p = yh * nx, q = yh;
        #pragma unroll
        for (int m = 32; m >= 1; m >>= 1) {
            p += __shfl_xor(p, m, 64);
            q += __shfl_xor(q, m, 64);
        }
        acc += log2f(p) - log2f(q);
    }
    if (wv == 0) {
        float a0 = exp2f((source[lane] + scores[(size_t)b * T_ * S_ + lane]) * LOG2E);
        float p = a0 * Zbuf[((size_t)b * CPB_) * 64 + lane];
        #pragma unroll
        for (int m = 32; m >= 1; m >>= 1) p += __shfl_xor(p, m, 64);
        acc += log2f(p);
    }
    if (lane == 0) part[wv] = acc;
    __syncthreads();
    if (threadIdx.x == 0) {
        float s = 0.f;
        #pragma unroll
        for (int i = 0; i < 16; ++i) s += part[i];
        out[b] = 0.6931471805599453f * s + 4.158883083359672f;  // ln2*log2Z + ln(64)
    }
}

extern "C" void kernel_launch(void* const* d_in, const int* in_sizes, int n_in,
                              void* d_out, int out_size, void* d_ws, size_t ws_size,
                              hipStream_t stream) {
    (void)in_sizes; (void)n_in; (void)out_size; (void)ws_size;
    const float* scores     = (const float*)d_in[0];
    const float* transition = (const float*)d_in[1];
    const float* source     = (const float*)d_in[2];
    const float* sink       = (const float*)d_in[3];
    float* out = (float*)d_out;

    float* Ybuf = (float*)d_ws;                          // B*CPB*64 floats (13.6 MB)
    float* Zbuf = Ybuf + (size_t)B_ * CPB_ * 64;         // 13.6 MB

    hipLaunchKernelGGL(crf_phase1, dim3(2 * B_ * WPB_), dim3(64), 0, stream,
                       scores, transition, Ybuf, Zbuf);
    hipLaunchKernelGGL(crf_phase2, dim3(B_), dim3(1024), 0, stream,
                       scores, source, sink, Ybuf, Zbuf, out);
}

// Round 5
// 123.862 us; speedup vs baseline: 1.5830x; 1.5830x over previous
//
#include <hip/hip_runtime.h>
#include <cstdint>

// Linear-chain CRF log-partition, B=64, T=4096, S=64.
// R5: R3 structure (NC=273 x L=15 chunked scan, mfma_f32_16x16x32_bf16,
// 16 chains/wave, rank-1 recombination) with two fixes from R4 post-mortem:
//  - depth-3 prefetch ring on the lane-divergent A-side emission loads
//    (the vmcnt wait was in the per-step dependent chain at depth 1)
//  - fragment-order coalesced dwordx4 stores for Y/Z (rank-1 dots are
//    permutation-invariant); trailing emission folded into phase2.

#define B_    64
#define T_    4096
#define S_    64
#define L_    15
#define NC_   273                 // 273*15 = 4095 = T_-1
#define WPB_  18                  // 16-chain wave-blocks per batch (18*16=288)
#define CPB_  288
#define LOG2E 1.44269504088896340736f

typedef float  f32x4  __attribute__((ext_vector_type(4)));
typedef __bf16 bf16x8 __attribute__((ext_vector_type(8)));
union U4B { uint4 u; bf16x8 b; };

__global__ __launch_bounds__(64, 3) void crf_phase1(
    const float* __restrict__ scores,      // (B,T,S)
    const float* __restrict__ transition,  // (S,S) [from,to]
    float* __restrict__ Ybuf, float* __restrict__ Zbuf, float* __restrict__ Lz)
{
    __shared__ float tb[16][68];
    const int wid  = blockIdx.x;
    const bool bwd = wid >= (B_ * WPB_);
    const int wl   = bwd ? wid - B_ * WPB_ : wid;
    const int b    = wl / WPB_, wg = wl % WPB_;
    const int lane = threadIdx.x, g = lane >> 4, l = lane & 15;

    // ---- E fragments in registers: fwd B[k][n]=exp(T[k][n]); bwd =exp(T[n][k])
    bf16x8 BE[2][4];
    #pragma unroll
    for (int kb = 0; kb < 2; ++kb)
    #pragma unroll
    for (int nt = 0; nt < 4; ++nt) {
        bf16x8 t;
        #pragma unroll
        for (int dd = 0; dd < 4; ++dd) {
            int k0 = 32 * kb + 8 * g + 2 * dd, n = 16 * nt + l;
            float e0, e1;
            if (!bwd) { e0 = transition[k0 * 64 + n]; e1 = transition[(k0 + 1) * 64 + n]; }
            else      { e0 = transition[n * 64 + k0]; e1 = transition[n * 64 + k0 + 1]; }
            t[2 * dd]     = (__bf16)exp2f(e0 * LOG2E);
            t[2 * dd + 1] = (__bf16)exp2f(e1 * LOG2E);
        }
        BE[kb][nt] = t;
    }

    // A-side emission pointer: chain = local row l, states 8g.. contiguous
    int cl = 16 * wg + l; if (cl > NC_ - 1) cl = NC_ - 1;
    const float* ap = scores + ((size_t)b * T_ + L_ * cl + (bwd ? L_ : 0)) * S_ + 8 * g;

    f32x4 acc[4];
    f32x4 ring[3][4];             // depth-3 prefetch ring (48 VGPRs)
    int   Lt[4] = {0, 0, 0, 0};

    auto ldq = [&](int idx, f32x4* q) {
        const float* p = ap + (ptrdiff_t)idx * S_;
        q[0] = *(const f32x4*)p;        q[1] = *(const f32x4*)(p + 4);
        q[2] = *(const f32x4*)(p + 32); q[3] = *(const f32x4*)(p + 36);
    };
    auto mfma8 = [&](bf16x8 A0, bf16x8 A1) {
        #pragma unroll
        for (int nt = 0; nt < 4; ++nt) {
            f32x4 z4 = {0.f, 0.f, 0.f, 0.f};
            z4      = __builtin_amdgcn_mfma_f32_16x16x32_bf16(A0, BE[0][nt], z4, 0, 0, 0);
            acc[nt] = __builtin_amdgcn_mfma_f32_16x16x32_bf16(A1, BE[1][nt], z4, 0, 0, 0);
        }
    };
    auto renorm = [&]() {
        #pragma unroll
        for (int r = 0; r < 4; ++r) {
            float m = fmaxf(fmaxf(acc[0][r], acc[1][r]), fmaxf(acc[2][r], acc[3][r]));
            m = fmaxf(m, __shfl_xor(m, 1, 64));
            m = fmaxf(m, __shfl_xor(m, 2, 64));
            m = fmaxf(m, __shfl_xor(m, 4, 64));
            m = fmaxf(m, __shfl_xor(m, 8, 64));
            int ex = (int)(__float_as_uint(m) >> 23) - 127;
            float sc = __uint_as_float((unsigned)(127 - ex) << 23);   // exact 2^-ex
            Lt[r] += ex;
            #pragma unroll
            for (int nt = 0; nt < 4; ++nt) acc[nt][r] *= sc;
        }
    };
    // transpose acc (C: chain 4g+r, state 16nt+l) -> per-lane A rows, * em, pack
    auto xposeA = [&](const f32x4& c0, const f32x4& c1,
                      const f32x4& c2, const f32x4& c3, bf16x8& A0, bf16x8& A1) {
        #pragma unroll
        for (int nt = 0; nt < 4; ++nt)
            #pragma unroll
            for (int r = 0; r < 4; ++r)
                tb[4 * g + r][16 * nt + l] = acc[nt][r];
        __builtin_amdgcn_s_waitcnt(0xC07F);        // lgkmcnt(0) only, vmcnt open
        __builtin_amdgcn_wave_barrier();
        const float* rowp = &tb[l][8 * g];
        f32x4 x0 = *(const f32x4*)rowp;
        f32x4 x1 = *(const f32x4*)(rowp + 4);
        f32x4 x2 = *(const f32x4*)(rowp + 32);
        f32x4 x3 = *(const f32x4*)(rowp + 36);
        #pragma unroll
        for (int d = 0; d < 4; ++d) {
            A0[d]     = (__bf16)(x0[d] * exp2f(c0[d] * LOG2E));
            A0[d + 4] = (__bf16)(x1[d] * exp2f(c1[d] * LOG2E));
            A1[d]     = (__bf16)(x2[d] * exp2f(c2[d] * LOG2E));
            A1[d + 4] = (__bf16)(x3[d] * exp2f(c3[d] * LOG2E));
        }
    };

    if (!bwd) {
        // y'_c = 1^T E d1 E d2 ... d14 E  (em rows t0+1..t0+14; d15 in phase2)
        ldq(1, ring[0]); ldq(2, ring[1]); ldq(3, ring[2]);
        { U4B t; t.u = make_uint4(0x3F803F80u, 0x3F803F80u, 0x3F803F80u, 0x3F803F80u);
          mfma8(t.b, t.b); }                       // tt=0: A = ones
        #pragma unroll
        for (int tt = 1; tt < L_; ++tt) {
            f32x4* q = ring[(tt - 1) % 3];
            f32x4 c0 = q[0], c1 = q[1], c2 = q[2], c3 = q[3];
            if (tt + 3 <= L_ - 1) ldq(tt + 3, ring[(tt - 1) % 3]);
            bf16x8 A0, A1;
            xposeA(c0, c1, c2, c3, A0, A1);
            mfma8(A0, A1);
            if ((tt & 3) == 3) renorm();
        }
        float* yb = Ybuf + ((size_t)(b * WPB_ + wg) << 10);
        #pragma unroll
        for (int nt = 0; nt < 4; ++nt)
            *(f32x4*)(yb + ((nt * 64 + lane) << 2)) = acc[nt];   // coalesced
    } else {
        // z_c = E d1 E d2 ... E d15 * 1, rows consumed descending (15..1)
        ldq(0, ring[0]); ldq(-1, ring[1]); ldq(-2, ring[2]);
        {   // i=0: A = em(row t0+15) (z = ones)
            f32x4* q = ring[0];
            bf16x8 A0, A1;
            #pragma unroll
            for (int d = 0; d < 4; ++d) {
                A0[d]     = (__bf16)exp2f(q[0][d] * LOG2E);
                A0[d + 4] = (__bf16)exp2f(q[1][d] * LOG2E);
                A1[d]     = (__bf16)exp2f(q[2][d] * LOG2E);
                A1[d + 4] = (__bf16)exp2f(q[3][d] * LOG2E);
            }
            mfma8(A0, A1);
            ldq(-3, ring[0]);
        }
        #pragma unroll
        for (int i = 1; i < L_; ++i) {
            f32x4* q = ring[i % 3];
            f32x4 c0 = q[0], c1 = q[1], c2 = q[2], c3 = q[3];
            if (i + 3 <= L_ - 1) ldq(-(i + 3), ring[i % 3]);
            bf16x8 A0, A1;
            xposeA(c0, c1, c2, c3, A0, A1);
            mfma8(A0, A1);
            if ((i & 3) == 3) renorm();
        }
        float* zb = Zbuf + ((size_t)(b * WPB_ + wg) << 10);
        #pragma unroll
        for (int nt = 0; nt < 4; ++nt)
            *(f32x4*)(zb + ((nt * 64 + lane) << 2)) = acc[nt];   // coalesced
        if (l == 0) {
            #pragma unroll
            for (int r = 0; r < 4; ++r)
                Lz[b * CPB_ + 16 * wg + 4 * g + r] = (float)Lt[r];
        }
    }
}

// ---------------------------------------------------------------------------
// phase2: rank-1 recombination on fragment-ordered blocks.
// Block position p -> (chain 4*(lane>>4)+r, state 16*nt+(lane&15)).
// p_c = sum_s y'_c[s] em_end_c[s] zn[s],  q_c = sum_s y'_c[s] em_end_c[s],
// term_c = log2 p_c - log2 q_c + Lz[c];  zn = z_{c+1} (esink for c=NC-1).
// ---------------------------------------------------------------------------
__global__ __launch_bounds__(512) void crf_phase2(
    const float* __restrict__ scores, const float* __restrict__ source,
    const float* __restrict__ sink,
    const float* __restrict__ Ybuf, const float* __restrict__ Zbuf,
    const float* __restrict__ Lz, float* __restrict__ out)
{
    __shared__ float part[8];
    const int b = blockIdx.x;
    const int wv = threadIdx.x >> 6, lane = threadIdx.x & 63;
    const int q = lane >> 4, l = lane & 15;
    float acc = 0.f;

    for (int wg = wv; wg < WPB_; wg += 8) {
        const float* Yb = Ybuf + ((size_t)(b * WPB_ + wg) << 10);
        const float* Zb = Zbuf + ((size_t)(b * WPB_ + wg) << 10);
        f32x4 y[4], z[4];
        #pragma unroll
        for (int nt = 0; nt < 4; ++nt) {
            y[nt] = *(const f32x4*)(Yb + ((nt * 64 + lane) << 2));
            z[nt] = *(const f32x4*)(Zb + ((nt * 64 + lane) << 2));
        }
        // em rows (end of each of this lane's 4 chunks), state 16nt+l
        float E2[4][4];
        #pragma unroll
        for (int r = 0; r < 4; ++r) {
            int c = 16 * wg + 4 * q + r; int cc = c < NC_ ? c : NC_ - 1;
            const float* er = scores + ((size_t)b * T_ + (size_t)15 * cc + 15) * S_;
            #pragma unroll
            for (int nt = 0; nt < 4; ++nt)
                E2[r][nt] = exp2f(er[16 * nt + l] * LOG2E);
        }
        // z_next for r==3: chunk (q+1,0), from quad q+1 (or next block if q==3)
        float zn3[4];
        #pragma unroll
        for (int nt = 0; nt < 4; ++nt) zn3[nt] = __shfl(z[nt][0], lane + 16, 64);
        if (q == 3 && wg + 1 < WPB_) {
            const float* Zn = Zbuf + ((size_t)(b * WPB_ + wg + 1) << 10);
            #pragma unroll
            for (int nt = 0; nt < 4; ++nt) zn3[nt] = Zn[(nt * 64 + l) << 2];
        }
        float esk[4];
        #pragma unroll
        for (int nt = 0; nt < 4; ++nt) esk[nt] = exp2f(sink[16 * nt + l] * LOG2E);

        #pragma unroll
        for (int r = 0; r < 4; ++r) {
            int c = 16 * wg + 4 * q + r;
            float p = 0.f, qs = 0.f;
            #pragma unroll
            for (int nt = 0; nt < 4; ++nt) {
                float zz = (r < 3) ? z[nt][r + 1] : zn3[nt];
                if (c == NC_ - 1) zz = esk[nt];
                float ye = y[nt][r] * E2[r][nt];
                p  += ye * zz;
                qs += ye;
            }
            #pragma unroll
            for (int m = 1; m <= 8; m <<= 1) {
                p  += __shfl_xor(p, m, 64);
                qs += __shfl_xor(qs, m, 64);
            }
            if (l == 0 && c < NC_)
                acc += log2f(p) - log2f(qs) + Lz[b * CPB_ + c];
        }
        if (wg == 0 && q == 0) {    // a0 . z_0 term
            float s0 = 0.f;
            #pragma unroll
            for (int nt = 0; nt < 4; ++nt) {
                float a0 = exp2f((source[16 * nt + l]
                                  + scores[(size_t)b * T_ * S_ + 16 * nt + l]) * LOG2E);
                s0 += a0 * z[nt][0];
            }
            #pragma unroll
            for (int m = 1; m <= 8; m <<= 1) s0 += __shfl_xor(s0, m, 64);
            if (l == 0) acc += log2f(s0);
        }
    }
    #pragma unroll
    for (int m = 32; m >= 1; m >>= 1) acc += __shfl_xor(acc, m, 64);
    if (lane == 0) part[wv] = acc;
    __syncthreads();
    if (threadIdx.x == 0) {
        float s = 0.f;
        #pragma unroll
        for (int i = 0; i < 8; ++i) s += part[i];
        out[b] = 0.6931471805599453f * s + 4.158883083359672f;  // ln2*log2Z + ln64
    }
}

extern "C" void kernel_launch(void* const* d_in, const int* in_sizes, int n_in,
                              void* d_out, int out_size, void* d_ws, size_t ws_size,
                              hipStream_t stream) {
    (void)in_sizes; (void)n_in; (void)out_size; (void)ws_size;
    const float* scores     = (const float*)d_in[0];
    const float* transition = (const float*)d_in[1];
    const float* source     = (const float*)d_in[2];
    const float* sink       = (const float*)d_in[3];
    float* out = (float*)d_out;

    float* Ybuf = (float*)d_ws;                          // 64*18*1024 f32 (4.7 MB)
    float* Zbuf = Ybuf + (size_t)B_ * WPB_ * 1024;       // 4.7 MB
    float* Lz   = Zbuf + (size_t)B_ * WPB_ * 1024;       // 73 KB

    hipLaunchKernelGGL(crf_phase1, dim3(2 * B_ * WPB_), dim3(64), 0, stream,
                       scores, transition, Ybuf, Zbuf, Lz);
    hipLaunchKernelGGL(crf_phase2, dim3(B_), dim3(512), 0, stream,
                       scores, source, sink, Ybuf, Zbuf, Lz, out);
}